// Round 1
// baseline (6153.162 us; speedup 1.0000x reference)
//
#include <hip/hip_runtime.h>
#include <cstddef>

#define CONF_THR 0.2f
#define IOU_THR  0.5f
#define IMG_SZ   448.0f

// ---------------------------------------------------------------------------
// Conv 3x3 pad=1 as implicit GEMM: C[m,n] = sum_k A[m,k]*B[k,n]
//   A = weights viewed as (Cout, Cin*9) row-major (OIHW is already this)
//   B = im2col of input, gathered on the fly
//   n = b*HWout + p  (batch-major pixel index), fused bias + leaky ReLU
// Tile: 64(m) x 64(n) x 16(k), 256 threads, 4x4 micro-tile per thread.
// ---------------------------------------------------------------------------
template<int STRIDE>
__global__ __launch_bounds__(256)
void conv_gemm(const float* __restrict__ x, const float* __restrict__ w,
               const float* __restrict__ bias, float* __restrict__ y,
               int Cin, int Hin, int Win, int Cout, int Hout, int Wout)
{
    const int K     = Cin * 9;
    const int HWout = Hout * Wout;
    const int Ntot  = 16 * HWout;
    const int m0 = blockIdx.x * 64;
    const int n0 = blockIdx.y * 64;

    __shared__ float As[16][68];   // [k][m], pad to 68 (272B rows, 16B-aligned)
    __shared__ float Bs[16][68];   // [k][n]

    const int tid = threadIdx.x;
    const int tx  = tid & 15;      // n-group for compute
    const int ty  = tid >> 4;      // m-group for compute

    // ---- B-gather thread mapping: one n per thread, 4 consecutive kk ----
    const int nB    = n0 + (tid & 63);
    const int kgrp  = (tid >> 6) * 4;          // 0,4,8,12
    const bool nvalid = (nB < Ntot);
    int bb = 0, oy = 0, ox = 0;
    if (nvalid) {
        bb = nB / HWout;
        int p = nB - bb * HWout;
        oy = p / Wout;
        ox = p - oy * Wout;
    }
    const int iy0 = oy * STRIDE - 1;
    const int ix0 = ox * STRIDE - 1;

    // ---- A-load thread mapping: 4 consecutive k per thread ----
    const int ar = tid >> 2;            // m offset 0..63
    const int ac = (tid & 3) * 4;       // k offset 0,4,8,12

    float acc[4][4] = {};

    for (int k0 = 0; k0 < K; k0 += 16) {
        // stage A (weights): float4, 64B-contiguous per 4 lanes
        {
            const float* ap = w + (size_t)(m0 + ar) * K + (k0 + ac);
            float4 av = *(const float4*)ap;
            As[ac + 0][ar] = av.x;
            As[ac + 1][ar] = av.y;
            As[ac + 2][ar] = av.z;
            As[ac + 3][ar] = av.w;
        }
        // stage B (im2col gather)
        #pragma unroll
        for (int q = 0; q < 4; ++q) {
            const int kk = kgrp + q;
            const int k  = k0 + kk;
            const int ic = k / 9;
            const int r9 = k - ic * 9;
            const int kh = r9 / 3;
            const int kw = r9 - kh * 3;
            const int iy = iy0 + kh;
            const int ix = ix0 + kw;
            float v = 0.f;
            if (nvalid && iy >= 0 && iy < Hin && ix >= 0 && ix < Win)
                v = x[(((size_t)bb * Cin + ic) * Hin + iy) * Win + ix];
            Bs[kk][tid & 63] = v;
        }
        __syncthreads();

        #pragma unroll
        for (int kk = 0; kk < 16; ++kk) {
            const float4 a  = *(const float4*)&As[kk][ty * 4];
            const float4 bv = *(const float4*)&Bs[kk][tx * 4];
            acc[0][0] = fmaf(a.x, bv.x, acc[0][0]);
            acc[0][1] = fmaf(a.x, bv.y, acc[0][1]);
            acc[0][2] = fmaf(a.x, bv.z, acc[0][2]);
            acc[0][3] = fmaf(a.x, bv.w, acc[0][3]);
            acc[1][0] = fmaf(a.y, bv.x, acc[1][0]);
            acc[1][1] = fmaf(a.y, bv.y, acc[1][1]);
            acc[1][2] = fmaf(a.y, bv.z, acc[1][2]);
            acc[1][3] = fmaf(a.y, bv.w, acc[1][3]);
            acc[2][0] = fmaf(a.z, bv.x, acc[2][0]);
            acc[2][1] = fmaf(a.z, bv.y, acc[2][1]);
            acc[2][2] = fmaf(a.z, bv.z, acc[2][2]);
            acc[2][3] = fmaf(a.z, bv.w, acc[2][3]);
            acc[3][0] = fmaf(a.w, bv.x, acc[3][0]);
            acc[3][1] = fmaf(a.w, bv.y, acc[3][1]);
            acc[3][2] = fmaf(a.w, bv.z, acc[3][2]);
            acc[3][3] = fmaf(a.w, bv.w, acc[3][3]);
        }
        __syncthreads();
    }

    // epilogue: bias + leaky ReLU, store NCHW
    #pragma unroll
    for (int i = 0; i < 4; ++i) {
        const int m = m0 + ty * 4 + i;
        const float bv = bias[m];
        #pragma unroll
        for (int j = 0; j < 4; ++j) {
            const int n = n0 + tx * 4 + j;
            if (n < Ntot) {
                float v = acc[i][j] + bv;
                v = (v >= 0.f) ? v : 0.1f * v;
                const int b2 = n / HWout;
                const int p  = n - b2 * HWout;
                y[((size_t)b2 * Cout + m) * HWout + p] = v;
            }
        }
    }
}

// ---------------------------------------------------------------------------
// fc1: out(16,4096) = x(16,50176) @ W(50176,4096); K split into 64 chunks of
// 784 for parallelism; deterministic two-stage reduction.
// Each thread: 2 columns (float2 W loads), acc[16][2].
// ---------------------------------------------------------------------------
__global__ __launch_bounds__(256)
void fc1_partial(const float* __restrict__ x, const float* __restrict__ w,
                 float* __restrict__ part)
{
    __shared__ float xs[196][16];   // [j][b]
    const int tid = threadIdx.x;
    const int n   = blockIdx.x * 512 + tid * 2;
    const int kc  = blockIdx.y;
    const int k0  = kc * 784;

    float acc[16][2] = {};

    for (int kt = 0; kt < 784; kt += 196) {
        __syncthreads();
        for (int i = tid; i < 16 * 196; i += 256) {
            const int j = i >> 4;
            const int b = i & 15;
            xs[j][b] = x[(size_t)b * 50176 + k0 + kt + j];
        }
        __syncthreads();
        for (int j = 0; j < 196; ++j) {
            const float2 wv = *(const float2*)&w[(size_t)(k0 + kt + j) * 4096 + n];
            #pragma unroll
            for (int b4 = 0; b4 < 4; ++b4) {
                const float4 xv = *(const float4*)&xs[j][b4 * 4];
                acc[b4*4+0][0] = fmaf(xv.x, wv.x, acc[b4*4+0][0]);
                acc[b4*4+0][1] = fmaf(xv.x, wv.y, acc[b4*4+0][1]);
                acc[b4*4+1][0] = fmaf(xv.y, wv.x, acc[b4*4+1][0]);
                acc[b4*4+1][1] = fmaf(xv.y, wv.y, acc[b4*4+1][1]);
                acc[b4*4+2][0] = fmaf(xv.z, wv.x, acc[b4*4+2][0]);
                acc[b4*4+2][1] = fmaf(xv.z, wv.y, acc[b4*4+2][1]);
                acc[b4*4+3][0] = fmaf(xv.w, wv.x, acc[b4*4+3][0]);
                acc[b4*4+3][1] = fmaf(xv.w, wv.y, acc[b4*4+3][1]);
            }
        }
    }

    #pragma unroll
    for (int b = 0; b < 16; ++b) {
        float2 o; o.x = acc[b][0]; o.y = acc[b][1];
        *(float2*)&part[((size_t)kc * 16 + b) * 4096 + n] = o;
    }
}

__global__ __launch_bounds__(256)
void fc1_reduce(const float* __restrict__ part, const float* __restrict__ bias,
                float* __restrict__ y)
{
    const int i = blockIdx.x * 256 + threadIdx.x;   // over 16*4096
    float s = 0.f;
    for (int kc = 0; kc < 64; ++kc) s += part[(size_t)kc * 65536 + i];
    s += bias[i & 4095];
    y[i] = (s >= 0.f) ? s : 0.1f * s;
}

// ---------------------------------------------------------------------------
// fc2: out(16,1470) = x(16,4096) @ W(4096,1470); K split into 32 chunks of 128.
// ---------------------------------------------------------------------------
__global__ __launch_bounds__(256)
void fc2_partial(const float* __restrict__ x, const float* __restrict__ w,
                 float* __restrict__ part)
{
    __shared__ float xs[128][16];
    const int tid = threadIdx.x;
    const int n   = blockIdx.x * 256 + tid;
    const int kc  = blockIdx.y;
    const int k0  = kc * 128;

    for (int i = tid; i < 128 * 16; i += 256) {
        const int j = i >> 4;
        const int b = i & 15;
        xs[j][b] = x[(size_t)b * 4096 + k0 + j];
    }
    __syncthreads();

    float acc[16] = {};
    if (n < 1470) {
        for (int j = 0; j < 128; ++j) {
            const float wv = w[(size_t)(k0 + j) * 1470 + n];
            #pragma unroll
            for (int b4 = 0; b4 < 4; ++b4) {
                const float4 xv = *(const float4*)&xs[j][b4 * 4];
                acc[b4*4+0] = fmaf(xv.x, wv, acc[b4*4+0]);
                acc[b4*4+1] = fmaf(xv.y, wv, acc[b4*4+1]);
                acc[b4*4+2] = fmaf(xv.z, wv, acc[b4*4+2]);
                acc[b4*4+3] = fmaf(xv.w, wv, acc[b4*4+3]);
            }
        }
        #pragma unroll
        for (int b = 0; b < 16; ++b)
            part[((size_t)kc * 16 + b) * 1470 + n] = acc[b];
    }
}

__global__ __launch_bounds__(256)
void fc2_reduce(const float* __restrict__ part, const float* __restrict__ bias,
                float* __restrict__ y)
{
    const int i = blockIdx.x * 256 + threadIdx.x;   // over 16*1470
    if (i >= 16 * 1470) return;
    float s = 0.f;
    for (int kc = 0; kc < 32; ++kc) s += part[(size_t)kc * 23520 + i];
    const int n = i % 1470;
    s += bias[n];
    y[i] = 1.0f / (1.0f + expf(-s));
}

// ---------------------------------------------------------------------------
// Decode + per-batch NMS (exactly mirrors JAX semantics incl. stable argsort)
// Box j: gA=j/14, gB=(j%14)/2, nb=j%2 ; value c at out2[b, gB*210+gA*30+nb*5+c]
// ---------------------------------------------------------------------------
__global__ __launch_bounds__(128)
void decode_nms(const float* __restrict__ out2, float* __restrict__ dout)
{
    const int b = blockIdx.x;
    const int t = threadIdx.x;
    const float cell = 1.0f / 7.0f;
    const float* o = out2 + (size_t)b * 1470;

    __shared__ float bx[98][4];
    __shared__ float sc[98];
    __shared__ float area[98];
    __shared__ int   order[98];
    __shared__ int   rankof[98];
    __shared__ int   supp[98];
    __shared__ int   keep_s[98];

    if (t < 98) {
        const int gA = t / 14;
        const int r  = t % 14;
        const int gB = r >> 1;
        const int nb = r & 1;
        const int base = gB * 210 + gA * 30 + nb * 5;
        const float v0 = o[base + 0];
        const float v1 = o[base + 1];
        const float w  = o[base + 2];
        const float h  = o[base + 3];
        const float s  = o[base + 4];
        const float cx = v0 * cell + (float)gA * cell;
        const float cy = v1 * cell + (float)gB * cell;
        const float x1 = cx - 0.5f * w;
        const float y1 = cy - 0.5f * h;
        const float x2 = cx + 0.5f * w;
        const float y2 = cy + 0.5f * h;
        bx[t][0] = x1; bx[t][1] = y1; bx[t][2] = x2; bx[t][3] = y2;
        sc[t] = s;
        area[t] = (x2 - x1) * (y2 - y1);
        supp[t] = 0;
        keep_s[t] = 0;
    }
    __syncthreads();

    // stable descending rank (ties -> lower original index first)
    if (t < 98) {
        const float si = (sc[t] >= CONF_THR) ? sc[t] : -1.0f;
        int rank = 0;
        for (int j = 0; j < 98; ++j) {
            const float sj = (sc[j] >= CONF_THR) ? sc[j] : -1.0f;
            rank += (sj > si) || (sj == si && j < t);
        }
        order[rank] = t;
        rankof[t] = rank;
    }
    __syncthreads();

    // greedy NMS in sorted order
    for (int i = 0; i < 98; ++i) {
        const int oi = order[i];
        const bool ki = (sc[oi] >= CONF_THR) && (supp[i] == 0);
        if (t == 0) keep_s[i] = ki ? 1 : 0;
        if (ki && t < 98 && t > i) {
            const int oj = order[t];
            const float xx1 = fmaxf(bx[oi][0], bx[oj][0]);
            const float yy1 = fmaxf(bx[oi][1], bx[oj][1]);
            const float xx2 = fminf(bx[oi][2], bx[oj][2]);
            const float yy2 = fminf(bx[oi][3], bx[oj][3]);
            const float iw = fmaxf(xx2 - xx1, 0.f);
            const float ih = fmaxf(yy2 - yy1, 0.f);
            const float inter = iw * ih;
            const float iou = inter / (area[oi] + area[oj] - inter);
            if (iou > IOU_THR) supp[t] = 1;
        }
        __syncthreads();
    }

    // outputs: boxes_px(16*98*4) | scores(16*98) | keep(16*98) | labels(16*49*20)
    float* out_boxes  = dout;
    float* out_scores = dout + 6272;
    float* out_keep   = dout + 7840;
    float* out_labels = dout + 9408;

    if (t < 98) {
        const bool kp = keep_s[rankof[t]] != 0;
        const size_t bi = ((size_t)b * 98 + t) * 4;
        out_boxes[bi + 0] = kp ? bx[t][0] * IMG_SZ : 0.f;
        out_boxes[bi + 1] = kp ? bx[t][1] * IMG_SZ : 0.f;
        out_boxes[bi + 2] = kp ? bx[t][2] * IMG_SZ : 0.f;
        out_boxes[bi + 3] = kp ? bx[t][3] * IMG_SZ : 0.f;
        out_scores[(size_t)b * 98 + t] = kp ? sc[t] : 0.f;
        out_keep[(size_t)b * 98 + t]   = kp ? 1.f : 0.f;
    }
    for (int i = t; i < 49 * 20; i += 128) {
        const int g  = i / 20;
        const int c  = i - g * 20;
        const int gA = g / 7;
        const int gB = g - gA * 7;
        out_labels[(size_t)b * 980 + i] = o[gB * 210 + gA * 30 + 10 + c];
    }
}

// ---------------------------------------------------------------------------
extern "C" void kernel_launch(void* const* d_in, const int* in_sizes, int n_in,
                              void* d_out, int out_size, void* d_ws, size_t ws_size,
                              hipStream_t stream)
{
    (void)in_sizes; (void)n_in; (void)out_size; (void)ws_size;

    const float* features = (const float*)d_in[0];
    const float* w1 = (const float*)d_in[1];
    const float* b1 = (const float*)d_in[2];
    const float* w2 = (const float*)d_in[3];
    const float* b2 = (const float*)d_in[4];
    const float* w3 = (const float*)d_in[5];
    const float* b3 = (const float*)d_in[6];
    const float* w4 = (const float*)d_in[7];
    const float* b4 = (const float*)d_in[8];
    const float* fc1_w = (const float*)d_in[9];
    const float* fc1_b = (const float*)d_in[10];
    const float* fc2_w = (const float*)d_in[11];
    const float* fc2_b = (const float*)d_in[12];

    float* ws = (float*)d_ws;
    // activations (a1..a3 region later reused by part1)
    float* a1 = ws;                               // 16*1024*196 = 3,211,264
    float* a2 = a1 + 3211264;                     // 16*1024*49  =   802,816
    float* a3 = a2 + 802816;                      //               802,816
    float* a4 = a3 + 802816;                      //               802,816
    float* part1 = ws;                            // 64*16*4096 = 4,194,304 (reuses a1..a3, dead by then)
    float* fc1o  = a4 + 802816;                   // 16*4096 = 65,536
    float* part2 = fc1o + 65536;                  // 32*16*1470 = 752,640
    float* fc2o  = part2 + 752640;                // 16*1470 = 23,520

    // conv1: 2048 -> 1024, 14x14, stride 1
    conv_gemm<1><<<dim3(16, 49), 256, 0, stream>>>(features, w1, b1, a1,
                                                   2048, 14, 14, 1024, 14, 14);
    // conv2: 1024 -> 1024, 14x14 -> 7x7, stride 2
    conv_gemm<2><<<dim3(16, 13), 256, 0, stream>>>(a1, w2, b2, a2,
                                                   1024, 14, 14, 1024, 7, 7);
    // conv3, conv4: 1024 -> 1024, 7x7, stride 1
    conv_gemm<1><<<dim3(16, 13), 256, 0, stream>>>(a2, w3, b3, a3,
                                                   1024, 7, 7, 1024, 7, 7);
    conv_gemm<1><<<dim3(16, 13), 256, 0, stream>>>(a3, w4, b4, a4,
                                                   1024, 7, 7, 1024, 7, 7);

    fc1_partial<<<dim3(8, 64), 256, 0, stream>>>(a4, fc1_w, part1);
    fc1_reduce<<<256, 256, 0, stream>>>(part1, fc1_b, fc1o);

    fc2_partial<<<dim3(6, 32), 256, 0, stream>>>(fc1o, fc2_w, part2);
    fc2_reduce<<<92, 256, 0, stream>>>(part2, fc2_b, fc2o);

    decode_nms<<<16, 128, 0, stream>>>(fc2o, (float*)d_out);
}

// Round 3
// 5367.236 us; speedup vs baseline: 1.1464x; 1.1464x over previous
//
#include <hip/hip_runtime.h>
#include <cstddef>

#define CONF_THR 0.2f
#define IOU_THR  0.5f
#define IMG_SZ   448.0f

typedef __attribute__((ext_vector_type(8))) short short8;   // 8 bf16 (4 VGPRs)
typedef __attribute__((ext_vector_type(4))) float f32x4;
typedef unsigned short u16;
typedef unsigned int   u32;

__device__ __forceinline__ u16 f2bf(float x) {
    u32 u = __float_as_uint(x);
    u32 r = u + 0x7fffu + ((u >> 16) & 1u);   // RNE
    return (u16)(r >> 16);
}
__device__ __forceinline__ float bf2f(u16 h) {
    return __uint_as_float(((u32)h) << 16);
}

// ---------------------------------------------------------------------------
// Split fp32 tensor into 3 bf16 planes (exact: hi+mid+lo == fp32 to ~1 ulp)
// ---------------------------------------------------------------------------
__global__ __launch_bounds__(256)
void split3_kernel(const float* __restrict__ x, u16* __restrict__ p,
                   long n, long PS)
{
    long i = (long)blockIdx.x * 256 + threadIdx.x;
    if (i >= n) return;
    float v = x[i];
    u16 h = f2bf(v);  float r  = v - bf2f(h);
    u16 m = f2bf(r);  float r2 = r - bf2f(m);
    u16 l = f2bf(r2);
    p[i] = h; p[PS + i] = m; p[2 * PS + i] = l;
}

// ---------------------------------------------------------------------------
// Conv-weight split to tap-major: w[Cout][Cin][9] fp32 ->
//   wT[plane(3)][tap(9)][Cout=1024][Cin] bf16   (plane stride 9*1024*Cin)
// ---------------------------------------------------------------------------
__global__ __launch_bounds__(256)
void wsplit_kernel(const float* __restrict__ w, u16* __restrict__ wT, int Cin)
{
    __shared__ float ws_l[2304];
    const int t  = threadIdx.x;
    const int cb = blockIdx.x;            // Cin / 256 chunks
    const int co = blockIdx.y;            // 0..1023
    const long base = ((long)co * Cin + cb * 256) * 9;
    for (int i = t; i < 2304; i += 256) ws_l[i] = w[base + i];
    __syncthreads();
    const int ci = cb * 256 + t;
    const long PS = (long)9 * 1024 * Cin;
    #pragma unroll
    for (int tap = 0; tap < 9; ++tap) {
        float v = ws_l[t * 9 + tap];
        u16 h = f2bf(v);  float r = v - bf2f(h);
        u16 m = f2bf(r);
        u16 l = f2bf(r - bf2f(m));
        long off = ((long)tap * 1024 + co) * Cin + ci;
        wT[off] = h; wT[PS + off] = m; wT[2 * PS + off] = l;
    }
}

// ---------------------------------------------------------------------------
// MFMA conv: C[m][n] = sum over 6 plane-pairs x 9 taps x Cin of A*B
//   A = wT panel (rows contiguous in ci), B = shifted activation copy.
// Tile 256(m) x 128(n) x 64(ci), 512 threads (8 waves, 4x2 of 64x64).
// LDS: A 32KB single-buf + B 2x16KB double-buf (=64KB), XOR-swizzled rows.
// Output: fp32 partials per blockIdx.z K-chunk -> reduce_ep.
// ---------------------------------------------------------------------------
template<int STRIDE>
__global__ __launch_bounds__(512)
void conv_mfma(const u16* __restrict__ xp, const u16* __restrict__ wT,
               float* __restrict__ partial, const int Cin,
               const int Hin, const int Win, const int Hout, const int Wout,
               const int Ntot, const int sppsh, const int steps_pb,
               const int Npad, const long PSx)
{
    __shared__ unsigned char Alds[256 * 128];
    __shared__ unsigned char Blds[2][128 * 128];

    const int t  = threadIdx.x;
    const int m0 = blockIdx.x * 256;
    const int n0 = blockIdx.y * 128;
    const int g0 = blockIdx.z * steps_pb;
    const int HWin  = Hin * Win;
    const int HWout = Hout * Wout;

    // ---- per-thread gather geometry (1 column, 16 ci per step) ----
    const int col = t & 127, cisub = t >> 7;
    const int n  = n0 + col;
    const bool vn = n < Ntot;
    const int nn = vn ? n : 0;
    const int b  = nn / HWout;
    const int rp = nn - b * HWout;
    const int oy = rp / Wout;
    const int ox = rp - oy * Wout;
    const long anchor = (long)b * Cin * HWin
                      + (long)(oy * STRIDE - 1) * Win + (ox * STRIDE - 1);
    u32 mask = 0;
    if (vn) {
        #pragma unroll
        for (int tp = 0; tp < 9; ++tp) {
            int iy = oy * STRIDE - 1 + tp / 3;
            int ix = ox * STRIDE - 1 + tp % 3;
            if (iy >= 0 && iy < Hin && ix >= 0 && ix < Win) mask |= 1u << tp;
        }
    }

    const int wid = t >> 6, l = t & 63;
    const int wm = wid >> 1, wn = wid & 1;
    const int l16 = l & 15, lhi = l >> 4;

    const f32x4 zero4 = {0.f, 0.f, 0.f, 0.f};
    f32x4 acc[4][4];
    #pragma unroll
    for (int i = 0; i < 4; ++i)
        #pragma unroll
        for (int j = 0; j < 4; ++j) acc[i][j] = zero4;

    uint4 aR[4];
    u32   vR[16];
    int pA = 0, pB = 0, tap = 0, ci0 = 0, tapoff = 0;
    bool okg = false;

    auto issue = [&](int g) {
        // phase decode: 6 plane-pairs x 9 taps x (Cin/64) ci-steps
        int phase = g >> sppsh;
        int cs    = g - (phase << sppsh);
        int pair  = phase / 9;
        tap       = phase - pair * 9;
        pA = (0x120100 >> (pair * 4)) & 15;   // hi,hi,mid,hi,lo,mid
        pB = (0x102010 >> (pair * 4)) & 15;   // hi,mid,hi,lo,hi,mid
        ci0 = cs * 64;
        // NOTE: anchor already contains the (-1,-1) pad shift; tapoff is the
        // RAW tap offset (kh*Win + kw). Round-2 bug: it subtracted 1 again.
        tapoff = (tap / 3) * Win + (tap % 3);
        okg = vn && ((mask >> tap) & 1u);
        // A: 4x16B coalesced chunks of the 256x64 weight panel
        const long abase = ((long)(pA * 9 + tap) * 1024 + m0) * Cin + ci0;
        #pragma unroll
        for (int c = 0; c < 4; ++c) {
            int idx = c * 512 + t;
            int row = idx >> 3, k8 = idx & 7;
            aR[c] = *(const uint4*)(wT + abase + (long)row * Cin + k8 * 8);
        }
        // B: 16 bf16 gathers (shifted copy; mask selects zero for pad/OOB)
        const u16* p = xp + (long)pB * PSx + anchor + tapoff
                     + (long)(ci0 + cisub * 16) * HWin;
        #pragma unroll
        for (int i = 0; i < 16; ++i) {
            u32 raw = p[(long)i * HWin];
            vR[i] = okg ? raw : 0u;
        }
    };

    auto commitB = [&](int buf) {
        u32 u[8];
        #pragma unroll
        for (int k = 0; k < 8; ++k)
            u[k] = (vR[2 * k] & 0xffffu) | (vR[2 * k + 1] << 16);
        const int swz = (col & 7) << 4;
        unsigned char* bp = &Blds[buf][col * 128];
        const int kb0 = cisub * 32;
        *(uint4*)(bp + ((kb0     ) ^ swz)) = make_uint4(u[0], u[1], u[2], u[3]);
        *(uint4*)(bp + ((kb0 + 16) ^ swz)) = make_uint4(u[4], u[5], u[6], u[7]);
    };

    auto commitA = [&]() {
        #pragma unroll
        for (int c = 0; c < 4; ++c) {
            int idx = c * 512 + t;
            int row = idx >> 3, kb = (idx & 7) << 4;
            *(uint4*)(&Alds[row * 128 + (kb ^ ((row & 7) << 4))]) = aR[c];
        }
    };

    auto compute = [&](int buf) {
        #pragma unroll
        for (int j = 0; j < 2; ++j) {
            const int kb = j * 64 + lhi * 16;
            short8 af[4], bfr[4];
            #pragma unroll
            for (int f = 0; f < 4; ++f) {
                int row = wm * 64 + f * 16 + l16;
                af[f] = *(const short8*)(&Alds[row * 128 + (kb ^ ((row & 7) << 4))]);
            }
            #pragma unroll
            for (int f = 0; f < 4; ++f) {
                int cc = wn * 64 + f * 16 + l16;
                bfr[f] = *(const short8*)(&Blds[buf][cc * 128 + (kb ^ ((cc & 7) << 4))]);
            }
            #pragma unroll
            for (int fm = 0; fm < 4; ++fm)
                #pragma unroll
                for (int fn = 0; fn < 4; ++fn)
                    acc[fm][fn] = __builtin_amdgcn_mfma_f32_16x16x32_bf16(
                        af[fm], bfr[fn], acc[fm][fn], 0, 0, 0);
        }
    };

    issue(g0);
    commitA();
    commitB(0);
    __syncthreads();

    for (int s = 0; s < steps_pb; ++s) {
        const int cur = s & 1;
        const bool more = (s + 1) < steps_pb;
        if (more) issue(g0 + s + 1);      // loads in flight under compute
        compute(cur);
        if (more) commitB(cur ^ 1);        // other B buffer: safe pre-barrier
        __syncthreads();                   // all A reads done
        if (more) commitA();               // overwrite single A buffer
        __syncthreads();
    }

    // fp32 partials: partial[z][1024][Npad]
    const long pbase = (long)blockIdx.z * 1024;
    #pragma unroll
    for (int fm = 0; fm < 4; ++fm) {
        #pragma unroll
        for (int r = 0; r < 4; ++r) {
            const long mrow = pbase + m0 + wm * 64 + fm * 16 + lhi * 4 + r;
            float* prow = partial + mrow * Npad + n0 + wn * 64 + l16;
            #pragma unroll
            for (int fn = 0; fn < 4; ++fn)
                prow[fn * 16] = acc[fm][fn][r];
        }
    }
}

// ---------------------------------------------------------------------------
// Sum K-chunk partials + bias + leakyReLU; emit bf16 3-plane split (MODE 1)
// or fp32 NCHW (MODE 0).
// ---------------------------------------------------------------------------
template<int MODE>
__global__ __launch_bounds__(256)
void reduce_ep(const float* __restrict__ partial, const float* __restrict__ bias,
               u16* __restrict__ yp, float* __restrict__ yf,
               const int S, const int Npad, const int Ntot, const int HWout,
               const long PSy)
{
    const long idx = (long)blockIdx.x * 256 + threadIdx.x;
    if (idx >= (long)1024 * Ntot) return;
    const int m = (int)(idx / Ntot);
    const int n = (int)(idx - (long)m * Ntot);
    float v = 0.f;
    for (int s = 0; s < S; ++s)
        v += partial[((long)s * 1024 + m) * Npad + n];
    v += bias[m];
    v = (v >= 0.f) ? v : 0.1f * v;
    const int b = n / HWout, pix = n - b * HWout;
    const long off = ((long)b * 1024 + m) * HWout + pix;
    if (MODE == 0) {
        yf[off] = v;
    } else {
        u16 h  = f2bf(v);  float r = v - bf2f(h);
        u16 mm = f2bf(r);
        u16 ll = f2bf(r - bf2f(mm));
        yp[off] = h; yp[PSy + off] = mm; yp[2 * PSy + off] = ll;
    }
}

// ---------------------------------------------------------------------------
// fc1: out(16,4096) = x(16,50176) @ W(50176,4096); K split into 64 chunks.
// ---------------------------------------------------------------------------
__global__ __launch_bounds__(256)
void fc1_partial(const float* __restrict__ x, const float* __restrict__ w,
                 float* __restrict__ part)
{
    __shared__ float xs[196][16];
    const int tid = threadIdx.x;
    const int n   = blockIdx.x * 512 + tid * 2;
    const int kc  = blockIdx.y;
    const int k0  = kc * 784;

    float acc[16][2] = {};

    for (int kt = 0; kt < 784; kt += 196) {
        __syncthreads();
        for (int i = tid; i < 16 * 196; i += 256) {
            const int j = i >> 4;
            const int b = i & 15;
            xs[j][b] = x[(size_t)b * 50176 + k0 + kt + j];
        }
        __syncthreads();
        for (int j = 0; j < 196; ++j) {
            const float2 wv = *(const float2*)&w[(size_t)(k0 + kt + j) * 4096 + n];
            #pragma unroll
            for (int b4 = 0; b4 < 4; ++b4) {
                const float4 xv = *(const float4*)&xs[j][b4 * 4];
                acc[b4*4+0][0] = fmaf(xv.x, wv.x, acc[b4*4+0][0]);
                acc[b4*4+0][1] = fmaf(xv.x, wv.y, acc[b4*4+0][1]);
                acc[b4*4+1][0] = fmaf(xv.y, wv.x, acc[b4*4+1][0]);
                acc[b4*4+1][1] = fmaf(xv.y, wv.y, acc[b4*4+1][1]);
                acc[b4*4+2][0] = fmaf(xv.z, wv.x, acc[b4*4+2][0]);
                acc[b4*4+2][1] = fmaf(xv.z, wv.y, acc[b4*4+2][1]);
                acc[b4*4+3][0] = fmaf(xv.w, wv.x, acc[b4*4+3][0]);
                acc[b4*4+3][1] = fmaf(xv.w, wv.y, acc[b4*4+3][1]);
            }
        }
    }

    #pragma unroll
    for (int b = 0; b < 16; ++b) {
        float2 o; o.x = acc[b][0]; o.y = acc[b][1];
        *(float2*)&part[((size_t)kc * 16 + b) * 4096 + n] = o;
    }
}

__global__ __launch_bounds__(256)
void fc1_reduce(const float* __restrict__ part, const float* __restrict__ bias,
                float* __restrict__ y)
{
    const int i = blockIdx.x * 256 + threadIdx.x;
    float s = 0.f;
    for (int kc = 0; kc < 64; ++kc) s += part[(size_t)kc * 65536 + i];
    s += bias[i & 4095];
    y[i] = (s >= 0.f) ? s : 0.1f * s;
}

// ---------------------------------------------------------------------------
// fc2: out(16,1470) = x(16,4096) @ W(4096,1470); K split into 32 chunks.
// ---------------------------------------------------------------------------
__global__ __launch_bounds__(256)
void fc2_partial(const float* __restrict__ x, const float* __restrict__ w,
                 float* __restrict__ part)
{
    __shared__ float xs[128][16];
    const int tid = threadIdx.x;
    const int n   = blockIdx.x * 256 + tid;
    const int kc  = blockIdx.y;
    const int k0  = kc * 128;

    for (int i = tid; i < 128 * 16; i += 256) {
        const int j = i >> 4;
        const int b = i & 15;
        xs[j][b] = x[(size_t)b * 4096 + k0 + j];
    }
    __syncthreads();

    float acc[16] = {};
    if (n < 1470) {
        for (int j = 0; j < 128; ++j) {
            const float wv = w[(size_t)(k0 + j) * 1470 + n];
            #pragma unroll
            for (int b4 = 0; b4 < 4; ++b4) {
                const float4 xv = *(const float4*)&xs[j][b4 * 4];
                acc[b4*4+0] = fmaf(xv.x, wv, acc[b4*4+0]);
                acc[b4*4+1] = fmaf(xv.y, wv, acc[b4*4+1]);
                acc[b4*4+2] = fmaf(xv.z, wv, acc[b4*4+2]);
                acc[b4*4+3] = fmaf(xv.w, wv, acc[b4*4+3]);
            }
        }
        #pragma unroll
        for (int b = 0; b < 16; ++b)
            part[((size_t)kc * 16 + b) * 1470 + n] = acc[b];
    }
}

__global__ __launch_bounds__(256)
void fc2_reduce(const float* __restrict__ part, const float* __restrict__ bias,
                float* __restrict__ y)
{
    const int i = blockIdx.x * 256 + threadIdx.x;
    if (i >= 16 * 1470) return;
    float s = 0.f;
    for (int kc = 0; kc < 32; ++kc) s += part[(size_t)kc * 23520 + i];
    const int n = i % 1470;
    s += bias[n];
    y[i] = 1.0f / (1.0f + expf(-s));
}

// ---------------------------------------------------------------------------
// Decode + per-batch NMS (mirrors JAX semantics incl. stable argsort)
// ---------------------------------------------------------------------------
__global__ __launch_bounds__(128)
void decode_nms(const float* __restrict__ out2, float* __restrict__ dout)
{
    const int b = blockIdx.x;
    const int t = threadIdx.x;
    const float cell = 1.0f / 7.0f;
    const float* o = out2 + (size_t)b * 1470;

    __shared__ float bx[98][4];
    __shared__ float sc[98];
    __shared__ float area[98];
    __shared__ int   order[98];
    __shared__ int   rankof[98];
    __shared__ int   supp[98];
    __shared__ int   keep_s[98];

    if (t < 98) {
        const int gA = t / 14;
        const int r  = t % 14;
        const int gB = r >> 1;
        const int nb = r & 1;
        const int base = gB * 210 + gA * 30 + nb * 5;
        const float v0 = o[base + 0];
        const float v1 = o[base + 1];
        const float w  = o[base + 2];
        const float h  = o[base + 3];
        const float s  = o[base + 4];
        const float cx = v0 * cell + (float)gA * cell;
        const float cy = v1 * cell + (float)gB * cell;
        const float x1 = cx - 0.5f * w;
        const float y1 = cy - 0.5f * h;
        const float x2 = cx + 0.5f * w;
        const float y2 = cy + 0.5f * h;
        bx[t][0] = x1; bx[t][1] = y1; bx[t][2] = x2; bx[t][3] = y2;
        sc[t] = s;
        area[t] = (x2 - x1) * (y2 - y1);
        supp[t] = 0;
        keep_s[t] = 0;
    }
    __syncthreads();

    if (t < 98) {
        const float si = (sc[t] >= CONF_THR) ? sc[t] : -1.0f;
        int rank = 0;
        for (int j = 0; j < 98; ++j) {
            const float sj = (sc[j] >= CONF_THR) ? sc[j] : -1.0f;
            rank += (sj > si) || (sj == si && j < t);
        }
        order[rank] = t;
        rankof[t] = rank;
    }
    __syncthreads();

    for (int i = 0; i < 98; ++i) {
        const int oi = order[i];
        const bool ki = (sc[oi] >= CONF_THR) && (supp[i] == 0);
        if (t == 0) keep_s[i] = ki ? 1 : 0;
        if (ki && t < 98 && t > i) {
            const int oj = order[t];
            const float xx1 = fmaxf(bx[oi][0], bx[oj][0]);
            const float yy1 = fmaxf(bx[oi][1], bx[oj][1]);
            const float xx2 = fminf(bx[oi][2], bx[oj][2]);
            const float yy2 = fminf(bx[oi][3], bx[oj][3]);
            const float iw = fmaxf(xx2 - xx1, 0.f);
            const float ih = fmaxf(yy2 - yy1, 0.f);
            const float inter = iw * ih;
            const float iou = inter / (area[oi] + area[oj] - inter);
            if (iou > IOU_THR) supp[t] = 1;
        }
        __syncthreads();
    }

    float* out_boxes  = dout;
    float* out_scores = dout + 6272;
    float* out_keep   = dout + 7840;
    float* out_labels = dout + 9408;

    if (t < 98) {
        const bool kp = keep_s[rankof[t]] != 0;
        const size_t bi = ((size_t)b * 98 + t) * 4;
        out_boxes[bi + 0] = kp ? bx[t][0] * IMG_SZ : 0.f;
        out_boxes[bi + 1] = kp ? bx[t][1] * IMG_SZ : 0.f;
        out_boxes[bi + 2] = kp ? bx[t][2] * IMG_SZ : 0.f;
        out_boxes[bi + 3] = kp ? bx[t][3] * IMG_SZ : 0.f;
        out_scores[(size_t)b * 98 + t] = kp ? sc[t] : 0.f;
        out_keep[(size_t)b * 98 + t]   = kp ? 1.f : 0.f;
    }
    for (int i = t; i < 49 * 20; i += 128) {
        const int g  = i / 20;
        const int c  = i - g * 20;
        const int gA = g / 7;
        const int gB = g - gA * 7;
        out_labels[(size_t)b * 980 + i] = o[gB * 210 + gA * 30 + 10 + c];
    }
}

// ---------------------------------------------------------------------------
extern "C" void kernel_launch(void* const* d_in, const int* in_sizes, int n_in,
                              void* d_out, int out_size, void* d_ws, size_t ws_size,
                              hipStream_t stream)
{
    (void)in_sizes; (void)n_in; (void)out_size; (void)ws_size;

    const float* features = (const float*)d_in[0];
    const float* w1 = (const float*)d_in[1];
    const float* b1 = (const float*)d_in[2];
    const float* w2 = (const float*)d_in[3];
    const float* b2 = (const float*)d_in[4];
    const float* w3 = (const float*)d_in[5];
    const float* b3 = (const float*)d_in[6];
    const float* w4 = (const float*)d_in[7];
    const float* b4 = (const float*)d_in[8];
    const float* fc1_w = (const float*)d_in[9];
    const float* fc1_b = (const float*)d_in[10];
    const float* fc2_w = (const float*)d_in[11];
    const float* fc2_b = (const float*)d_in[12];

    // workspace plan (~252 MB total; gathers over/under-shoot stay inside ws)
    char* W = (char*)d_ws;
    size_t o = 0;
    auto alloc = [&](size_t bytes) -> char* {
        char* r = W + o; o += (bytes + 255) & ~(size_t)255; return r;
    };
    u16*   wT      = (u16*)  alloc(113246208ULL); // 3*9*1024*2048*2 (max, reused per layer)
    u16*   xp      = (u16*)  alloc(38535168ULL);  // features 3-plane
    u16*   actA    = (u16*)  alloc(19267584ULL);  // a1 planes
    u16*   actB    = (u16*)  alloc(4816896ULL);   // a2 then a3 planes
    float* a4      = (float*)alloc(3211264ULL);   // conv4 out fp32
    float* partial = (float*)alloc(52428800ULL);  // max 4*1024*3200*4
    float* part1   = (float*)alloc(16777216ULL);
    float* fc1o    = (float*)alloc(262144ULL);
    float* part2   = (float*)alloc(3010560ULL);
    float* fc2o    = (float*)alloc(94080ULL);
    (void)alloc(4096);                            // tail guard

    // split features -> 3 bf16 planes
    split3_kernel<<<25088, 256, 0, stream>>>(features, xp, 6422528L, 6422528L);

    // conv1: 2048->1024, 14x14; 54 phases * 32 = 1728 steps, S=4
    wsplit_kernel<<<dim3(8, 1024), 256, 0, stream>>>(w1, wT, 2048);
    conv_mfma<1><<<dim3(4, 25, 4), 512, 0, stream>>>(
        xp, wT, partial, 2048, 14, 14, 14, 14, 3136, 5, 432, 3200, 6422528L);
    reduce_ep<1><<<12544, 256, 0, stream>>>(partial, b1, actA, nullptr,
                                            4, 3200, 3136, 196, 3211264L);

    // conv2: 1024->1024, stride 2; 54*16 = 864 steps, S=8
    wsplit_kernel<<<dim3(4, 1024), 256, 0, stream>>>(w2, wT, 1024);
    conv_mfma<2><<<dim3(4, 7, 8), 512, 0, stream>>>(
        actA, wT, partial, 1024, 14, 14, 7, 7, 784, 4, 108, 896, 3211264L);
    reduce_ep<1><<<3136, 256, 0, stream>>>(partial, b2, actB, nullptr,
                                           8, 896, 784, 49, 802816L);

    // conv3
    wsplit_kernel<<<dim3(4, 1024), 256, 0, stream>>>(w3, wT, 1024);
    conv_mfma<1><<<dim3(4, 7, 8), 512, 0, stream>>>(
        actB, wT, partial, 1024, 7, 7, 7, 7, 784, 4, 108, 896, 802816L);
    reduce_ep<1><<<3136, 256, 0, stream>>>(partial, b3, actB, nullptr,
                                           8, 896, 784, 49, 802816L);

    // conv4 -> fp32 a4
    wsplit_kernel<<<dim3(4, 1024), 256, 0, stream>>>(w4, wT, 1024);
    conv_mfma<1><<<dim3(4, 7, 8), 512, 0, stream>>>(
        actB, wT, partial, 1024, 7, 7, 7, 7, 784, 4, 108, 896, 802816L);
    reduce_ep<0><<<3136, 256, 0, stream>>>(partial, b4, nullptr, a4,
                                           8, 896, 784, 49, 0L);

    // fc1 / fc2 / decode (unchanged, known-good)
    fc1_partial<<<dim3(8, 64), 256, 0, stream>>>(a4, fc1_w, part1);
    fc1_reduce<<<256, 256, 0, stream>>>(part1, fc1_b, fc1o);

    fc2_partial<<<dim3(6, 32), 256, 0, stream>>>(fc1o, fc2_w, part2);
    fc2_reduce<<<92, 256, 0, stream>>>(part2, fc2_b, fc2o);

    decode_nms<<<16, 128, 0, stream>>>(fc2o, (float*)d_out);
}

// Round 4
// 1529.513 us; speedup vs baseline: 4.0230x; 3.5091x over previous
//
#include <hip/hip_runtime.h>
#include <cstddef>

#define CONF_THR 0.2f
#define IOU_THR  0.5f
#define IMG_SZ   448.0f

typedef __attribute__((ext_vector_type(8))) short short8;   // 8 bf16 (4 VGPRs)
typedef __attribute__((ext_vector_type(4))) float f32x4;
typedef unsigned short u16;
typedef unsigned int   u32;

__device__ __forceinline__ u16 f2bf(float x) {
    u32 u = __float_as_uint(x);
    u32 r = u + 0x7fffu + ((u >> 16) & 1u);   // RNE
    return (u16)(r >> 16);
}
__device__ __forceinline__ float bf2f(u16 h) {
    return __uint_as_float(((u32)h) << 16);
}

// global -> LDS direct (16B per lane; LDS dest = wave-uniform base + lane*16)
#define GLOAD_LDS16(gsrc, ldst)                                              \
    __builtin_amdgcn_global_load_lds(                                        \
        (const __attribute__((address_space(1))) void*)(gsrc),               \
        (__attribute__((address_space(3))) void*)(ldst), 16, 0, 0)

// ---------------------------------------------------------------------------
// features (NCHW fp32) -> 3 bf16 planes, NHWC zero-PADDED:
//   plane[b][py(16)][px(16)][ci(2048)], borders = 0
// ---------------------------------------------------------------------------
__global__ __launch_bounds__(256)
void pad_split(const float* __restrict__ x, u16* __restrict__ xp,
               const int Cin, const int H, const int W,
               const int PW, const int PHW, const long PS)
{
    __shared__ float lds[64][200];
    const int t  = threadIdx.x;
    const int b  = blockIdx.x >> 5;       // Cin=2048 -> 32 ci-chunks of 64
    const int cc = blockIdx.x & 31;
    const int ci0 = cc * 64;
    const int HW = H * W;

    for (int r = 0; r < 64; ++r) {
        for (int i = t; i < HW; i += 256)
            lds[r][i] = x[((long)b * Cin + ci0 + r) * HW + i];
    }
    __syncthreads();

    const int lci = t & 63;
    const int lp  = t >> 6;
    for (int pp = 0; pp < PHW / 4; ++pp) {
        const int pix = pp * 4 + lp;
        const int py = pix / PW, px = pix % PW;
        float v = 0.f;
        if (py >= 1 && py <= H && px >= 1 && px <= W)
            v = lds[lci][(py - 1) * W + (px - 1)];
        u16 h = f2bf(v);  float r = v - bf2f(h);
        u16 m = f2bf(r);
        u16 l = f2bf(r - bf2f(m));
        const long off = ((long)b * PHW + pix) * Cin + ci0 + lci;
        xp[off] = h; xp[PS + off] = m; xp[2 * PS + off] = l;
    }
}

// ---------------------------------------------------------------------------
// Conv-weight split to tap-major: w[Cout][Cin][9] fp32 ->
//   wT[plane(3)][tap(9)][Cout=1024][Cin] bf16
// ---------------------------------------------------------------------------
__global__ __launch_bounds__(256)
void wsplit_kernel(const float* __restrict__ w, u16* __restrict__ wT, int Cin)
{
    __shared__ float ws_l[2304];
    const int t  = threadIdx.x;
    const int cb = blockIdx.x;
    const int co = blockIdx.y;
    const long base = ((long)co * Cin + cb * 256) * 9;
    for (int i = t; i < 2304; i += 256) ws_l[i] = w[base + i];
    __syncthreads();
    const int ci = cb * 256 + t;
    const long PS = (long)9 * 1024 * Cin;
    #pragma unroll
    for (int tap = 0; tap < 9; ++tap) {
        float v = ws_l[t * 9 + tap];
        u16 h = f2bf(v);  float r = v - bf2f(h);
        u16 m = f2bf(r);
        u16 l = f2bf(r - bf2f(m));
        long off = ((long)tap * 1024 + co) * Cin + ci;
        wT[off] = h; wT[PS + off] = m; wT[2 * PS + off] = l;
    }
}

// ---------------------------------------------------------------------------
// MFMA conv, m97-style staging. Tile 256m x 128n x 64ci, 512 thr (8 waves).
// A,B single-buffered LDS (48KB) staged by global_load_lds with pre-swizzled
// per-lane sources; XOR-swizzled ds_read_b128; 5 limb-pairs (hh,hm,mh,hl,lh).
// B reads come from zero-PADDED NHWC planes -> no masking at all.
// ---------------------------------------------------------------------------
template<int STRIDE>
__global__ __launch_bounds__(512, 4)
void conv_mfma(const u16* __restrict__ xp, const u16* __restrict__ wT,
               float* __restrict__ partial,
               const int Cin, const int PW, const int PHW,
               const int Wout, const int Ntot,
               const int sppsh, const int steps_pb, const int Npad,
               const long PSx)
{
    __shared__ u16 Alds[256 * 64];   // 32KB: [row(256)][64ci], rows swizzled
    __shared__ u16 Blds[128 * 64];   // 16KB: [col(128)][64ci]

    const int t  = threadIdx.x;
    const int m0 = blockIdx.x * 256;
    const int n0 = blockIdx.y * 128;
    const int g0 = blockIdx.z * steps_pb;
    const int HWout = Wout * Wout;

    // ---- B source precompute (2 calls; col/blk static per thread) ----
    int bpix[2], bblk[2];
    #pragma unroll
    for (int c = 0; c < 2; ++c) {
        const int idx = c * 512 + t;
        const int col = idx >> 3;
        const int blk = idx & 7;
        int n = n0 + col; if (n >= Ntot) n = 0;   // junk cols: valid reads
        const int b  = n / HWout;
        const int rp = n - b * HWout;
        const int oy = rp / Wout;
        const int ox = rp - oy * Wout;
        bpix[c] = b * PHW + oy * STRIDE * PW + ox * STRIDE; // padded top-left
        bblk[c] = (blk ^ (col & 7)) * 8;          // pre-swizzled ci-block
    }
    // ---- A source precompute ----
    const int arow = t >> 3;                          // 0..63 within row-group
    const int ablk = ((t & 7) ^ (arow & 7)) * 8;      // pre-swizzled ci-block
    const int wbase = (t & 448) * 16;                 // wave-uniform LDS base

    const int wid = t >> 6, l = t & 63;
    const int wm = wid >> 1, wn = wid & 1;
    const int l16 = l & 15, lhi = l >> 4;

    const f32x4 zero4 = {0.f, 0.f, 0.f, 0.f};
    f32x4 acc[4][4];
    #pragma unroll
    for (int i = 0; i < 4; ++i)
        #pragma unroll
        for (int j = 0; j < 4; ++j) acc[i][j] = zero4;

    for (int s = 0; s < steps_pb; ++s) {
        const int g     = g0 + s;
        const int phase = g >> sppsh;
        const int cs    = g - (phase << sppsh);
        const int pair  = phase / 9;
        const int tap   = phase - pair * 9;
        const int pA = (0x20100 >> (pair * 4)) & 15;  // h,h,m,h,l
        const int pB = (0x02010 >> (pair * 4)) & 15;  // h,m,h,l,h
        const int ci0 = cs * 64;
        const int tapoff = (tap / 3) * PW + (tap % 3); // pad baked into layout

        // stage A: 256 rows x 128B, 4 gl_lds calls
        const u16* Ag = wT + ((long)(pA * 9 + tap) * 1024 + m0) * Cin + ci0 + ablk;
        #pragma unroll
        for (int c = 0; c < 4; ++c)
            GLOAD_LDS16(Ag + (long)(c * 64 + arow) * Cin,
                        (char*)Alds + c * 8192 + wbase);
        // stage B: 128 cols x 128B, 2 gl_lds calls
        const u16* Bg = xp + (long)pB * PSx + (long)tapoff * Cin + ci0;
        #pragma unroll
        for (int c = 0; c < 2; ++c)
            GLOAD_LDS16(Bg + (long)bpix[c] * Cin + bblk[c],
                        (char*)Blds + c * 8192 + wbase);

        __syncthreads();   // compiler drains vmcnt before s_barrier (m97)

        #pragma unroll
        for (int j = 0; j < 2; ++j) {
            const int kb = j * 64 + lhi * 16;
            short8 af[4], bf[4];
            #pragma unroll
            for (int f = 0; f < 4; ++f) {
                const int row = wm * 64 + f * 16 + l16;
                af[f] = *(const short8*)((const char*)Alds + row * 128
                                         + (kb ^ ((row & 7) << 4)));
            }
            #pragma unroll
            for (int f = 0; f < 4; ++f) {
                const int cc = wn * 64 + f * 16 + l16;
                bf[f] = *(const short8*)((const char*)Blds + cc * 128
                                         + (kb ^ ((cc & 7) << 4)));
            }
            #pragma unroll
            for (int fm = 0; fm < 4; ++fm)
                #pragma unroll
                for (int fn = 0; fn < 4; ++fn)
                    acc[fm][fn] = __builtin_amdgcn_mfma_f32_16x16x32_bf16(
                        af[fm], bf[fn], acc[fm][fn], 0, 0, 0);
        }
        __syncthreads();   // all reads done before next stage overwrites
    }

    // fp32 partials: partial[z][1024][Npad]
    const long pbase = (long)blockIdx.z * 1024;
    #pragma unroll
    for (int fm = 0; fm < 4; ++fm) {
        #pragma unroll
        for (int r = 0; r < 4; ++r) {
            const long mrow = pbase + m0 + wm * 64 + fm * 16 + lhi * 4 + r;
            float* prow = partial + mrow * Npad + n0 + wn * 64 + l16;
            #pragma unroll
            for (int fn = 0; fn < 4; ++fn)
                prow[fn * 16] = acc[fm][fn][r];
        }
    }
}

// ---------------------------------------------------------------------------
// Sum K-chunk partials + bias + leakyReLU -> NHWC-padded bf16 3-plane out.
// LDS transpose: coalesced n-major reads, coalesced ci-minor writes.
// ---------------------------------------------------------------------------
__global__ __launch_bounds__(256)
void reduce_nhwc(const float* __restrict__ partial, const float* __restrict__ bias,
                 u16* __restrict__ yp,
                 const int S, const int Npad, const int Ntot,
                 const int Wout, const int PW, const int PHW, const long PSy)
{
    __shared__ float lds[64][65];
    const int t  = threadIdx.x;
    const int m0 = blockIdx.x * 64;
    const int n0 = blockIdx.y * 64;
    const int HWout = Wout * Wout;

    const int lm = t >> 6, ln = t & 63;
    for (int r = 0; r < 16; ++r) {
        const int m = r * 4 + lm;
        const int n = n0 + ln;
        float v = 0.f;
        if (n < Ntot) {
            for (int s = 0; s < S; ++s)
                v += partial[((long)s * 1024 + m0 + m) * Npad + n];
            v += bias[m0 + m];
            v = (v >= 0.f) ? v : 0.1f * v;
        }
        lds[m][ln] = v;
    }
    __syncthreads();

    const int wn_ = t >> 6, wci = t & 63;
    for (int r = 0; r < 16; ++r) {
        const int pr = r * 4 + wn_;
        const int nn = n0 + pr;
        if (nn < Ntot) {
            const int b = nn / HWout;
            const int p = nn - b * HWout;
            const int py = p / Wout + 1, px = p % Wout + 1;
            const long off = ((long)b * PHW + py * PW + px) * 1024 + m0 + wci;
            const float v = lds[wci][pr];
            u16 h  = f2bf(v);  float rr = v - bf2f(h);
            u16 mm = f2bf(rr);
            u16 ll = f2bf(rr - bf2f(mm));
            yp[off] = h; yp[PSy + off] = mm; yp[2 * PSy + off] = ll;
        }
    }
}

// ---------------------------------------------------------------------------
// conv4 epilogue: partials -> fp32 NCHW (feeds fc1)
// ---------------------------------------------------------------------------
__global__ __launch_bounds__(256)
void reduce_f32(const float* __restrict__ partial, const float* __restrict__ bias,
                float* __restrict__ yf,
                const int S, const int Npad, const int Ntot, const int HWout)
{
    const long idx = (long)blockIdx.x * 256 + threadIdx.x;
    if (idx >= (long)1024 * Ntot) return;
    const int m = (int)(idx / Ntot);
    const int n = (int)(idx - (long)m * Ntot);
    float v = 0.f;
    for (int s = 0; s < S; ++s)
        v += partial[((long)s * 1024 + m) * Npad + n];
    v += bias[m];
    v = (v >= 0.f) ? v : 0.1f * v;
    const int b = n / HWout, pix = n - b * HWout;
    yf[((long)b * 1024 + m) * HWout + pix] = v;
}

// ---------------------------------------------------------------------------
// fc1: out(16,4096) = x(16,50176) @ W(50176,4096); K split into 64 chunks.
// ---------------------------------------------------------------------------
__global__ __launch_bounds__(256)
void fc1_partial(const float* __restrict__ x, const float* __restrict__ w,
                 float* __restrict__ part)
{
    __shared__ float xs[196][16];
    const int tid = threadIdx.x;
    const int n   = blockIdx.x * 512 + tid * 2;
    const int kc  = blockIdx.y;
    const int k0  = kc * 784;

    float acc[16][2] = {};

    for (int kt = 0; kt < 784; kt += 196) {
        __syncthreads();
        for (int i = tid; i < 16 * 196; i += 256) {
            const int j = i >> 4;
            const int b = i & 15;
            xs[j][b] = x[(size_t)b * 50176 + k0 + kt + j];
        }
        __syncthreads();
        for (int j = 0; j < 196; ++j) {
            const float2 wv = *(const float2*)&w[(size_t)(k0 + kt + j) * 4096 + n];
            #pragma unroll
            for (int b4 = 0; b4 < 4; ++b4) {
                const float4 xv = *(const float4*)&xs[j][b4 * 4];
                acc[b4*4+0][0] = fmaf(xv.x, wv.x, acc[b4*4+0][0]);
                acc[b4*4+0][1] = fmaf(xv.x, wv.y, acc[b4*4+0][1]);
                acc[b4*4+1][0] = fmaf(xv.y, wv.x, acc[b4*4+1][0]);
                acc[b4*4+1][1] = fmaf(xv.y, wv.y, acc[b4*4+1][1]);
                acc[b4*4+2][0] = fmaf(xv.z, wv.x, acc[b4*4+2][0]);
                acc[b4*4+2][1] = fmaf(xv.z, wv.y, acc[b4*4+2][1]);
                acc[b4*4+3][0] = fmaf(xv.w, wv.x, acc[b4*4+3][0]);
                acc[b4*4+3][1] = fmaf(xv.w, wv.y, acc[b4*4+3][1]);
            }
        }
    }

    #pragma unroll
    for (int b = 0; b < 16; ++b) {
        float2 o; o.x = acc[b][0]; o.y = acc[b][1];
        *(float2*)&part[((size_t)kc * 16 + b) * 4096 + n] = o;
    }
}

__global__ __launch_bounds__(256)
void fc1_reduce(const float* __restrict__ part, const float* __restrict__ bias,
                float* __restrict__ y)
{
    const int i = blockIdx.x * 256 + threadIdx.x;
    float s = 0.f;
    for (int kc = 0; kc < 64; ++kc) s += part[(size_t)kc * 65536 + i];
    s += bias[i & 4095];
    y[i] = (s >= 0.f) ? s : 0.1f * s;
}

// ---------------------------------------------------------------------------
// fc2: out(16,1470) = x(16,4096) @ W(4096,1470); K split into 32 chunks.
// ---------------------------------------------------------------------------
__global__ __launch_bounds__(256)
void fc2_partial(const float* __restrict__ x, const float* __restrict__ w,
                 float* __restrict__ part)
{
    __shared__ float xs[128][16];
    const int tid = threadIdx.x;
    const int n   = blockIdx.x * 256 + tid;
    const int kc  = blockIdx.y;
    const int k0  = kc * 128;

    for (int i = tid; i < 128 * 16; i += 256) {
        const int j = i >> 4;
        const int b = i & 15;
        xs[j][b] = x[(size_t)b * 4096 + k0 + j];
    }
    __syncthreads();

    float acc[16] = {};
    if (n < 1470) {
        for (int j = 0; j < 128; ++j) {
            const float wv = w[(size_t)(k0 + j) * 1470 + n];
            #pragma unroll
            for (int b4 = 0; b4 < 4; ++b4) {
                const float4 xv = *(const float4*)&xs[j][b4 * 4];
                acc[b4*4+0] = fmaf(xv.x, wv, acc[b4*4+0]);
                acc[b4*4+1] = fmaf(xv.y, wv, acc[b4*4+1]);
                acc[b4*4+2] = fmaf(xv.z, wv, acc[b4*4+2]);
                acc[b4*4+3] = fmaf(xv.w, wv, acc[b4*4+3]);
            }
        }
        #pragma unroll
        for (int b = 0; b < 16; ++b)
            part[((size_t)kc * 16 + b) * 1470 + n] = acc[b];
    }
}

__global__ __launch_bounds__(256)
void fc2_reduce(const float* __restrict__ part, const float* __restrict__ bias,
                float* __restrict__ y)
{
    const int i = blockIdx.x * 256 + threadIdx.x;
    if (i >= 16 * 1470) return;
    float s = 0.f;
    for (int kc = 0; kc < 32; ++kc) s += part[(size_t)kc * 23520 + i];
    const int n = i % 1470;
    s += bias[n];
    y[i] = 1.0f / (1.0f + expf(-s));
}

// ---------------------------------------------------------------------------
// Decode + per-batch NMS (mirrors JAX semantics incl. stable argsort)
// ---------------------------------------------------------------------------
__global__ __launch_bounds__(128)
void decode_nms(const float* __restrict__ out2, float* __restrict__ dout)
{
    const int b = blockIdx.x;
    const int t = threadIdx.x;
    const float cell = 1.0f / 7.0f;
    const float* o = out2 + (size_t)b * 1470;

    __shared__ float bx[98][4];
    __shared__ float sc[98];
    __shared__ float area[98];
    __shared__ int   order[98];
    __shared__ int   rankof[98];
    __shared__ int   supp[98];
    __shared__ int   keep_s[98];

    if (t < 98) {
        const int gA = t / 14;
        const int r  = t % 14;
        const int gB = r >> 1;
        const int nb = r & 1;
        const int base = gB * 210 + gA * 30 + nb * 5;
        const float v0 = o[base + 0];
        const float v1 = o[base + 1];
        const float w  = o[base + 2];
        const float h  = o[base + 3];
        const float s  = o[base + 4];
        const float cx = v0 * cell + (float)gA * cell;
        const float cy = v1 * cell + (float)gB * cell;
        const float x1 = cx - 0.5f * w;
        const float y1 = cy - 0.5f * h;
        const float x2 = cx + 0.5f * w;
        const float y2 = cy + 0.5f * h;
        bx[t][0] = x1; bx[t][1] = y1; bx[t][2] = x2; bx[t][3] = y2;
        sc[t] = s;
        area[t] = (x2 - x1) * (y2 - y1);
        supp[t] = 0;
        keep_s[t] = 0;
    }
    __syncthreads();

    if (t < 98) {
        const float si = (sc[t] >= CONF_THR) ? sc[t] : -1.0f;
        int rank = 0;
        for (int j = 0; j < 98; ++j) {
            const float sj = (sc[j] >= CONF_THR) ? sc[j] : -1.0f;
            rank += (sj > si) || (sj == si && j < t);
        }
        order[rank] = t;
        rankof[t] = rank;
    }
    __syncthreads();

    for (int i = 0; i < 98; ++i) {
        const int oi = order[i];
        const bool ki = (sc[oi] >= CONF_THR) && (supp[i] == 0);
        if (t == 0) keep_s[i] = ki ? 1 : 0;
        if (ki && t < 98 && t > i) {
            const int oj = order[t];
            const float xx1 = fmaxf(bx[oi][0], bx[oj][0]);
            const float yy1 = fmaxf(bx[oi][1], bx[oj][1]);
            const float xx2 = fminf(bx[oi][2], bx[oj][2]);
            const float yy2 = fminf(bx[oi][3], bx[oj][3]);
            const float iw = fmaxf(xx2 - xx1, 0.f);
            const float ih = fmaxf(yy2 - yy1, 0.f);
            const float inter = iw * ih;
            const float iou = inter / (area[oi] + area[oj] - inter);
            if (iou > IOU_THR) supp[t] = 1;
        }
        __syncthreads();
    }

    float* out_boxes  = dout;
    float* out_scores = dout + 6272;
    float* out_keep   = dout + 7840;
    float* out_labels = dout + 9408;

    if (t < 98) {
        const bool kp = keep_s[rankof[t]] != 0;
        const size_t bi = ((size_t)b * 98 + t) * 4;
        out_boxes[bi + 0] = kp ? bx[t][0] * IMG_SZ : 0.f;
        out_boxes[bi + 1] = kp ? bx[t][1] * IMG_SZ : 0.f;
        out_boxes[bi + 2] = kp ? bx[t][2] * IMG_SZ : 0.f;
        out_boxes[bi + 3] = kp ? bx[t][3] * IMG_SZ : 0.f;
        out_scores[(size_t)b * 98 + t] = kp ? sc[t] : 0.f;
        out_keep[(size_t)b * 98 + t]   = kp ? 1.f : 0.f;
    }
    for (int i = t; i < 49 * 20; i += 128) {
        const int g  = i / 20;
        const int c  = i - g * 20;
        const int gA = g / 7;
        const int gB = g - gA * 7;
        out_labels[(size_t)b * 980 + i] = o[gB * 210 + gA * 30 + 10 + c];
    }
}

// ---------------------------------------------------------------------------
extern "C" void kernel_launch(void* const* d_in, const int* in_sizes, int n_in,
                              void* d_out, int out_size, void* d_ws, size_t ws_size,
                              hipStream_t stream)
{
    (void)in_sizes; (void)n_in; (void)out_size; (void)ws_size;

    const float* features = (const float*)d_in[0];
    const float* w1 = (const float*)d_in[1];
    const float* b1 = (const float*)d_in[2];
    const float* w2 = (const float*)d_in[3];
    const float* b2 = (const float*)d_in[4];
    const float* w3 = (const float*)d_in[5];
    const float* b3 = (const float*)d_in[6];
    const float* w4 = (const float*)d_in[7];
    const float* b4 = (const float*)d_in[8];
    const float* fc1_w = (const float*)d_in[9];
    const float* fc1_b = (const float*)d_in[10];
    const float* fc2_w = (const float*)d_in[11];
    const float* fc2_b = (const float*)d_in[12];

    // ---- workspace plan (~248 MB; aliasing documented per-buffer) ----
    char* W = (char*)d_ws;
    size_t o = 0;
    auto alloc = [&](size_t bytes) -> char* {
        char* r = W + o; o += (bytes + 255) & ~(size_t)255; return r;
    };
    u16*   wT      = (u16*)  alloc(113246208ULL); // 3*9*1024*2048*2 (per-layer reuse)
    u16*   xp      = (u16*)  alloc(50331648ULL);  // features: 3*16*256*2048*2
    u16*   actA    = (u16*)  alloc(25165824ULL);  // conv1 out: 3*16*256*1024*2
    float* a4      = (float*)alloc(3211264ULL);   // conv4 out fp32 NCHW
    float* partial = (float*)alloc(52428800ULL);  // max(4*1024*3200, 12*1024*896)*4
    float* fc1o    = (float*)alloc(262144ULL);
    float* part2   = (float*)alloc(3010560ULL);
    float* fc2o    = (float*)alloc(94080ULL);
    (void)alloc(4096);
    // aliases inside xp (xp dead after conv1's conv_mfma):
    float* part1 = (float*)xp;                    // 16.8MB, live fc1 only
    u16*   actB  = (u16*)(xp + (24u << 20) / 2);  // 8MB @ xp+24MB, live conv2..conv4

    const long PSxp = 8388608L;   // 16*256*2048
    const long PSa  = 4194304L;   // 16*256*1024
    const long PSb  = 1327104L;   // 16*81*1024

    // features -> padded NHWC 3-plane
    pad_split<<<512, 256, 0, stream>>>(features, xp, 2048, 14, 14, 16, 256, PSxp);

    // conv1: Cin=2048, 14x14; 45 phases * 32 cs = 1440 steps, z=4
    wsplit_kernel<<<dim3(8, 1024), 256, 0, stream>>>(w1, wT, 2048);
    hipMemsetAsync(actA, 0, 25165824ULL, stream);      // zero pads once
    conv_mfma<1><<<dim3(4, 25, 4), 512, 0, stream>>>(
        xp, wT, partial, 2048, 16, 256, 14, 3136, 5, 360, 3200, PSxp);
    hipMemsetAsync(actB, 0, 7962624ULL, stream);       // xp dead now; zero pads
    reduce_nhwc<<<dim3(16, 49), 256, 0, stream>>>(partial, b1, actA,
                                                  4, 3200, 3136, 14, 16, 256, PSa);

    // conv2: Cin=1024, 14x14 -> 7x7 stride 2; 45*16=720 steps, z=12
    wsplit_kernel<<<dim3(4, 1024), 256, 0, stream>>>(w2, wT, 1024);
    conv_mfma<2><<<dim3(4, 7, 12), 512, 0, stream>>>(
        actA, wT, partial, 1024, 16, 256, 7, 784, 4, 60, 896, PSa);
    reduce_nhwc<<<dim3(16, 13), 256, 0, stream>>>(partial, b2, actB,
                                                  12, 896, 784, 7, 9, 81, PSb);

    // conv3: 7x7, padded 9x9
    wsplit_kernel<<<dim3(4, 1024), 256, 0, stream>>>(w3, wT, 1024);
    conv_mfma<1><<<dim3(4, 7, 12), 512, 0, stream>>>(
        actB, wT, partial, 1024, 9, 81, 7, 784, 4, 60, 896, PSb);
    reduce_nhwc<<<dim3(16, 13), 256, 0, stream>>>(partial, b3, actB,
                                                  12, 896, 784, 7, 9, 81, PSb);

    // conv4 -> fp32 NCHW a4
    wsplit_kernel<<<dim3(4, 1024), 256, 0, stream>>>(w4, wT, 1024);
    conv_mfma<1><<<dim3(4, 7, 12), 512, 0, stream>>>(
        actB, wT, partial, 1024, 9, 81, 7, 784, 4, 60, 896, PSb);
    reduce_f32<<<3136, 256, 0, stream>>>(partial, b4, a4, 12, 896, 784, 49);

    // fc1 / fc2 / decode (unchanged, known-good)
    fc1_partial<<<dim3(8, 64), 256, 0, stream>>>(a4, fc1_w, part1);
    fc1_reduce<<<256, 256, 0, stream>>>(part1, fc1_b, fc1o);

    fc2_partial<<<dim3(6, 32), 256, 0, stream>>>(fc1o, fc2_w, part2);
    fc2_reduce<<<92, 256, 0, stream>>>(part2, fc2_b, fc2o);

    decode_nms<<<16, 128, 0, stream>>>(fc2o, (float*)d_out);
}

// Round 5
// 1130.757 us; speedup vs baseline: 5.4416x; 1.3526x over previous
//
#include <hip/hip_runtime.h>
#include <cstddef>

#define CONF_THR 0.2f
#define IOU_THR  0.5f
#define IMG_SZ   448.0f

typedef __attribute__((ext_vector_type(8))) _Float16 half8;  // 8 f16 (4 VGPRs)
typedef __attribute__((ext_vector_type(4))) float f32x4;
typedef unsigned short u16;
typedef unsigned int   u32;

// fp16 RNE convert helpers (v_cvt_f16_f32 / v_cvt_f32_f16)
__device__ __forceinline__ u16 f2h(float x) {
    _Float16 h = (_Float16)x;
    return __builtin_bit_cast(u16, h);
}
__device__ __forceinline__ float h2f(u16 b) {
    _Float16 h = __builtin_bit_cast(_Float16, b);
    return (float)h;
}

// global -> LDS direct (16B per lane; LDS dest = wave-uniform base + lane*16)
#define GLOAD_LDS16(gsrc, ldst)                                              \
    __builtin_amdgcn_global_load_lds(                                        \
        (const __attribute__((address_space(1))) void*)(gsrc),               \
        (__attribute__((address_space(3))) void*)(ldst), 16, 0, 0)

// ---------------------------------------------------------------------------
// features (NCHW fp32) -> 2 fp16 limb planes of (x * 16), NHWC zero-PADDED:
//   plane[b][py(16)][px(16)][ci(2048)], borders = 0
// ---------------------------------------------------------------------------
__global__ __launch_bounds__(256)
void pad_split(const float* __restrict__ x, u16* __restrict__ xp,
               const int Cin, const int H, const int W,
               const int PW, const int PHW, const long PS)
{
    __shared__ float lds[64][200];
    const int t  = threadIdx.x;
    const int b  = blockIdx.x >> 5;       // Cin=2048 -> 32 ci-chunks of 64
    const int cc = blockIdx.x & 31;
    const int ci0 = cc * 64;
    const int HW = H * W;

    for (int r = 0; r < 64; ++r) {
        for (int i = t; i < HW; i += 256)
            lds[r][i] = x[((long)b * Cin + ci0 + r) * HW + i];
    }
    __syncthreads();

    const int lci = t & 63;
    const int lp  = t >> 6;
    for (int pp = 0; pp < PHW / 4; ++pp) {
        const int pix = pp * 4 + lp;
        const int py = pix / PW, px = pix % PW;
        float v = 0.f;
        if (py >= 1 && py <= H && px >= 1 && px <= W)
            v = lds[lci][(py - 1) * W + (px - 1)];
        v *= 16.0f;                               // activation scale
        u16 h = f2h(v);
        u16 m = f2h(v - h2f(h));
        const long off = ((long)b * PHW + pix) * Cin + ci0 + lci;
        xp[off] = h; xp[PS + off] = m;
    }
}

// ---------------------------------------------------------------------------
// Conv-weight split to tap-major fp16 limbs of (w * 256):
//   wT[plane(2)][tap(9)][Cout=1024][Cin]   (plane stride 9*1024*Cin)
// ---------------------------------------------------------------------------
__global__ __launch_bounds__(256)
void wsplit_kernel(const float* __restrict__ w, u16* __restrict__ wT, int Cin)
{
    __shared__ float ws_l[2304];
    const int t  = threadIdx.x;
    const int cb = blockIdx.x;
    const int co = blockIdx.y;
    const long base = ((long)co * Cin + cb * 256) * 9;
    for (int i = t; i < 2304; i += 256) ws_l[i] = w[base + i];
    __syncthreads();
    const int ci = cb * 256 + t;
    const long PS = (long)9 * 1024 * Cin;
    #pragma unroll
    for (int tap = 0; tap < 9; ++tap) {
        float v = ws_l[t * 9 + tap] * 256.0f;     // weight scale
        u16 h = f2h(v);
        u16 m = f2h(v - h2f(h));
        long off = ((long)tap * 1024 + co) * Cin + ci;
        wT[off] = h; wT[PS + off] = m;
    }
}

// ---------------------------------------------------------------------------
// MFMA conv, m97-style staging, fp16 2-limb x 3 pairs (hh, hm, mh).
// Tile 256m x 128n x 64ci, 512 thr (8 waves). A,B single-buffered LDS (48KB)
// staged via global_load_lds with pre-swizzled sources; XOR-swizzled
// ds_read_b128. Raw accumulator = 4096 * true (weights x256, acts x16).
// ---------------------------------------------------------------------------
template<int STRIDE>
__global__ __launch_bounds__(512, 4)
void conv_mfma(const u16* __restrict__ xp, const u16* __restrict__ wT,
               float* __restrict__ partial,
               const int Cin, const int PW, const int PHW,
               const int Wout, const int Ntot,
               const int sppsh, const int steps_pb, const int Npad,
               const long PSx)
{
    __shared__ u16 Alds[256 * 64];   // 32KB
    __shared__ u16 Blds[128 * 64];   // 16KB

    const int t  = threadIdx.x;
    const int m0 = blockIdx.x * 256;
    const int n0 = blockIdx.y * 128;
    const int g0 = blockIdx.z * steps_pb;
    const int HWout = Wout * Wout;

    // ---- B source precompute ----
    int bpix[2], bblk[2];
    #pragma unroll
    for (int c = 0; c < 2; ++c) {
        const int idx = c * 512 + t;
        const int col = idx >> 3;
        const int blk = idx & 7;
        int n = n0 + col; if (n >= Ntot) n = 0;
        const int b  = n / HWout;
        const int rp = n - b * HWout;
        const int oy = rp / Wout;
        const int ox = rp - oy * Wout;
        bpix[c] = b * PHW + oy * STRIDE * PW + ox * STRIDE;
        bblk[c] = (blk ^ (col & 7)) * 8;
    }
    // ---- A source precompute ----
    const int arow = t >> 3;
    const int ablk = ((t & 7) ^ (arow & 7)) * 8;
    const int wbase = (t & 448) * 16;

    const int wid = t >> 6, l = t & 63;
    const int wm = wid >> 1, wn = wid & 1;
    const int l16 = l & 15, lhi = l >> 4;

    const f32x4 zero4 = {0.f, 0.f, 0.f, 0.f};
    f32x4 acc[4][4];
    #pragma unroll
    for (int i = 0; i < 4; ++i)
        #pragma unroll
        for (int j = 0; j < 4; ++j) acc[i][j] = zero4;

    for (int s = 0; s < steps_pb; ++s) {
        const int g     = g0 + s;
        const int phase = g >> sppsh;
        const int cs    = g - (phase << sppsh);
        const int pair  = phase / 9;                 // 0,1,2
        const int tap   = phase - pair * 9;
        const int pA = (0x100 >> (pair * 4)) & 15;   // h,h,m
        const int pB = (0x010 >> (pair * 4)) & 15;   // h,m,h
        const int ci0 = cs * 64;
        const int tapoff = (tap / 3) * PW + (tap % 3);

        const u16* Ag = wT + ((long)(pA * 9 + tap) * 1024 + m0) * Cin + ci0 + ablk;
        #pragma unroll
        for (int c = 0; c < 4; ++c)
            GLOAD_LDS16(Ag + (long)(c * 64 + arow) * Cin,
                        (char*)Alds + c * 8192 + wbase);
        const u16* Bg = xp + (long)pB * PSx + (long)tapoff * Cin + ci0;
        #pragma unroll
        for (int c = 0; c < 2; ++c)
            GLOAD_LDS16(Bg + (long)bpix[c] * Cin + bblk[c],
                        (char*)Blds + c * 8192 + wbase);

        __syncthreads();

        #pragma unroll
        for (int j = 0; j < 2; ++j) {
            const int kb = j * 64 + lhi * 16;
            half8 af[4], bf[4];
            #pragma unroll
            for (int f = 0; f < 4; ++f) {
                const int row = wm * 64 + f * 16 + l16;
                af[f] = *(const half8*)((const char*)Alds + row * 128
                                        + (kb ^ ((row & 7) << 4)));
            }
            #pragma unroll
            for (int f = 0; f < 4; ++f) {
                const int cc = wn * 64 + f * 16 + l16;
                bf[f] = *(const half8*)((const char*)Blds + cc * 128
                                        + (kb ^ ((cc & 7) << 4)));
            }
            #pragma unroll
            for (int fm = 0; fm < 4; ++fm)
                #pragma unroll
                for (int fn = 0; fn < 4; ++fn)
                    acc[fm][fn] = __builtin_amdgcn_mfma_f32_16x16x32_f16(
                        af[fm], bf[fn], acc[fm][fn], 0, 0, 0);
        }
        __syncthreads();
    }

    const long pbase = (long)blockIdx.z * 1024;
    #pragma unroll
    for (int fm = 0; fm < 4; ++fm) {
        #pragma unroll
        for (int r = 0; r < 4; ++r) {
            const long mrow = pbase + m0 + wm * 64 + fm * 16 + lhi * 4 + r;
            float* prow = partial + mrow * Npad + n0 + wn * 64 + l16;
            #pragma unroll
            for (int fn = 0; fn < 4; ++fn)
                prow[fn * 16] = acc[fm][fn][r];
        }
    }
}

// ---------------------------------------------------------------------------
// Sum K-chunk partials, /4096 + bias + leakyReLU -> padded NHWC fp16 2-plane.
// ---------------------------------------------------------------------------
__global__ __launch_bounds__(256)
void reduce_nhwc(const float* __restrict__ partial, const float* __restrict__ bias,
                 u16* __restrict__ yp,
                 const int S, const int Npad, const int Ntot,
                 const int Wout, const int PW, const int PHW, const long PSy)
{
    __shared__ float lds[64][65];
    const int t  = threadIdx.x;
    const int m0 = blockIdx.x * 64;
    const int n0 = blockIdx.y * 64;
    const int HWout = Wout * Wout;

    const int lm = t >> 6, ln = t & 63;
    for (int r = 0; r < 16; ++r) {
        const int m = r * 4 + lm;
        const int n = n0 + ln;
        float v = 0.f;
        if (n < Ntot) {
            for (int s = 0; s < S; ++s)
                v += partial[((long)s * 1024 + m0 + m) * Npad + n];
            v = v * (1.0f / 4096.0f) + bias[m0 + m];
            v = (v >= 0.f) ? v : 0.1f * v;
        }
        lds[m][ln] = v;
    }
    __syncthreads();

    const int wn_ = t >> 6, wci = t & 63;
    for (int r = 0; r < 16; ++r) {
        const int pr = r * 4 + wn_;
        const int nn = n0 + pr;
        if (nn < Ntot) {
            const int b = nn / HWout;
            const int p = nn - b * HWout;
            const int py = p / Wout + 1, px = p % Wout + 1;
            const long off = ((long)b * PHW + py * PW + px) * 1024 + m0 + wci;
            const float vs = lds[wci][pr] * 16.0f;   // activation scale
            u16 h = f2h(vs);
            u16 m = f2h(vs - h2f(h));
            yp[off] = h; yp[PSy + off] = m;
        }
    }
}

// ---------------------------------------------------------------------------
// conv4 epilogue: partials -> fp32 NCHW (feeds fc1)
// ---------------------------------------------------------------------------
__global__ __launch_bounds__(256)
void reduce_f32(const float* __restrict__ partial, const float* __restrict__ bias,
                float* __restrict__ yf,
                const int S, const int Npad, const int Ntot, const int HWout)
{
    const long idx = (long)blockIdx.x * 256 + threadIdx.x;
    if (idx >= (long)1024 * Ntot) return;
    const int m = (int)(idx / Ntot);
    const int n = (int)(idx - (long)m * Ntot);
    float v = 0.f;
    for (int s = 0; s < S; ++s)
        v += partial[((long)s * 1024 + m) * Npad + n];
    v = v * (1.0f / 4096.0f) + bias[m];
    v = (v >= 0.f) ? v : 0.1f * v;
    const int b = n / HWout, pix = n - b * HWout;
    yf[((long)b * 1024 + m) * HWout + pix] = v;
}

// ---------------------------------------------------------------------------
// fc1: out(16,4096) = x(16,50176) @ W(50176,4096); 98 K-chunks of 512.
// Each thread: 4 columns (float4 W loads), acc[16][4].
// ---------------------------------------------------------------------------
__global__ __launch_bounds__(256)
void fc1_partial(const float* __restrict__ x, const float* __restrict__ w,
                 float* __restrict__ part)
{
    __shared__ float xs[512][16];   // 32KB
    const int tid = threadIdx.x;
    const int n   = blockIdx.x * 1024 + tid * 4;
    const int kc  = blockIdx.y;
    const int k0  = kc * 512;

    for (int i = tid; i < 512 * 16; i += 256) {
        const int j = i >> 4;
        const int b = i & 15;
        xs[j][b] = x[(size_t)b * 50176 + k0 + j];
    }
    __syncthreads();

    f32x4 acc[16];
    #pragma unroll
    for (int b = 0; b < 16; ++b) acc[b] = (f32x4){0.f, 0.f, 0.f, 0.f};

    for (int j = 0; j < 512; ++j) {
        const f32x4 wv = *(const f32x4*)&w[(size_t)(k0 + j) * 4096 + n];
        #pragma unroll
        for (int b = 0; b < 16; ++b) {
            const float xb = xs[j][b];
            #pragma unroll
            for (int c = 0; c < 4; ++c)
                acc[b][c] = fmaf(xb, wv[c], acc[b][c]);
        }
    }

    #pragma unroll
    for (int b = 0; b < 16; ++b)
        *(f32x4*)&part[((size_t)kc * 16 + b) * 4096 + n] = acc[b];
}

__global__ __launch_bounds__(256)
void fc1_reduce(const float* __restrict__ part, const float* __restrict__ bias,
                float* __restrict__ y)
{
    const int i = blockIdx.x * 256 + threadIdx.x;
    float s = 0.f;
    for (int kc = 0; kc < 98; ++kc) s += part[(size_t)kc * 65536 + i];
    s += bias[i & 4095];
    y[i] = (s >= 0.f) ? s : 0.1f * s;
}

// ---------------------------------------------------------------------------
// fc2: out(16,1470) = x(16,4096) @ W(4096,1470); K split into 32 chunks.
// ---------------------------------------------------------------------------
__global__ __launch_bounds__(256)
void fc2_partial(const float* __restrict__ x, const float* __restrict__ w,
                 float* __restrict__ part)
{
    __shared__ float xs[128][16];
    const int tid = threadIdx.x;
    const int n   = blockIdx.x * 256 + tid;
    const int kc  = blockIdx.y;
    const int k0  = kc * 128;

    for (int i = tid; i < 128 * 16; i += 256) {
        const int j = i >> 4;
        const int b = i & 15;
        xs[j][b] = x[(size_t)b * 4096 + k0 + j];
    }
    __syncthreads();

    float acc[16] = {};
    if (n < 1470) {
        for (int j = 0; j < 128; ++j) {
            const float wv = w[(size_t)(k0 + j) * 1470 + n];
            #pragma unroll
            for (int b4 = 0; b4 < 4; ++b4) {
                const float4 xv = *(const float4*)&xs[j][b4 * 4];
                acc[b4*4+0] = fmaf(xv.x, wv, acc[b4*4+0]);
                acc[b4*4+1] = fmaf(xv.y, wv, acc[b4*4+1]);
                acc[b4*4+2] = fmaf(xv.z, wv, acc[b4*4+2]);
                acc[b4*4+3] = fmaf(xv.w, wv, acc[b4*4+3]);
            }
        }
        #pragma unroll
        for (int b = 0; b < 16; ++b)
            part[((size_t)kc * 16 + b) * 1470 + n] = acc[b];
    }
}

__global__ __launch_bounds__(256)
void fc2_reduce(const float* __restrict__ part, const float* __restrict__ bias,
                float* __restrict__ y)
{
    const int i = blockIdx.x * 256 + threadIdx.x;
    if (i >= 16 * 1470) return;
    float s = 0.f;
    for (int kc = 0; kc < 32; ++kc) s += part[(size_t)kc * 23520 + i];
    const int n = i % 1470;
    s += bias[n];
    y[i] = 1.0f / (1.0f + expf(-s));
}

// ---------------------------------------------------------------------------
// Decode + per-batch NMS (mirrors JAX semantics incl. stable argsort)
// ---------------------------------------------------------------------------
__global__ __launch_bounds__(128)
void decode_nms(const float* __restrict__ out2, float* __restrict__ dout)
{
    const int b = blockIdx.x;
    const int t = threadIdx.x;
    const float cell = 1.0f / 7.0f;
    const float* o = out2 + (size_t)b * 1470;

    __shared__ float bx[98][4];
    __shared__ float sc[98];
    __shared__ float area[98];
    __shared__ int   order[98];
    __shared__ int   rankof[98];
    __shared__ int   supp[98];
    __shared__ int   keep_s[98];

    if (t < 98) {
        const int gA = t / 14;
        const int r  = t % 14;
        const int gB = r >> 1;
        const int nb = r & 1;
        const int base = gB * 210 + gA * 30 + nb * 5;
        const float v0 = o[base + 0];
        const float v1 = o[base + 1];
        const float w  = o[base + 2];
        const float h  = o[base + 3];
        const float s  = o[base + 4];
        const float cx = v0 * cell + (float)gA * cell;
        const float cy = v1 * cell + (float)gB * cell;
        const float x1 = cx - 0.5f * w;
        const float y1 = cy - 0.5f * h;
        const float x2 = cx + 0.5f * w;
        const float y2 = cy + 0.5f * h;
        bx[t][0] = x1; bx[t][1] = y1; bx[t][2] = x2; bx[t][3] = y2;
        sc[t] = s;
        area[t] = (x2 - x1) * (y2 - y1);
        supp[t] = 0;
        keep_s[t] = 0;
    }
    __syncthreads();

    if (t < 98) {
        const float si = (sc[t] >= CONF_THR) ? sc[t] : -1.0f;
        int rank = 0;
        for (int j = 0; j < 98; ++j) {
            const float sj = (sc[j] >= CONF_THR) ? sc[j] : -1.0f;
            rank += (sj > si) || (sj == si && j < t);
        }
        order[rank] = t;
        rankof[t] = rank;
    }
    __syncthreads();

    for (int i = 0; i < 98; ++i) {
        const int oi = order[i];
        const bool ki = (sc[oi] >= CONF_THR) && (supp[i] == 0);
        if (t == 0) keep_s[i] = ki ? 1 : 0;
        if (ki && t < 98 && t > i) {
            const int oj = order[t];
            const float xx1 = fmaxf(bx[oi][0], bx[oj][0]);
            const float yy1 = fmaxf(bx[oi][1], bx[oj][1]);
            const float xx2 = fminf(bx[oi][2], bx[oj][2]);
            const float yy2 = fminf(bx[oi][3], bx[oj][3]);
            const float iw = fmaxf(xx2 - xx1, 0.f);
            const float ih = fmaxf(yy2 - yy1, 0.f);
            const float inter = iw * ih;
            const float iou = inter / (area[oi] + area[oj] - inter);
            if (iou > IOU_THR) supp[t] = 1;
        }
        __syncthreads();
    }

    float* out_boxes  = dout;
    float* out_scores = dout + 6272;
    float* out_keep   = dout + 7840;
    float* out_labels = dout + 9408;

    if (t < 98) {
        const bool kp = keep_s[rankof[t]] != 0;
        const size_t bi = ((size_t)b * 98 + t) * 4;
        out_boxes[bi + 0] = kp ? bx[t][0] * IMG_SZ : 0.f;
        out_boxes[bi + 1] = kp ? bx[t][1] * IMG_SZ : 0.f;
        out_boxes[bi + 2] = kp ? bx[t][2] * IMG_SZ : 0.f;
        out_boxes[bi + 3] = kp ? bx[t][3] * IMG_SZ : 0.f;
        out_scores[(size_t)b * 98 + t] = kp ? sc[t] : 0.f;
        out_keep[(size_t)b * 98 + t]   = kp ? 1.f : 0.f;
    }
    for (int i = t; i < 49 * 20; i += 128) {
        const int g  = i / 20;
        const int c  = i - g * 20;
        const int gA = g / 7;
        const int gB = g - gA * 7;
        out_labels[(size_t)b * 980 + i] = o[gB * 210 + gA * 30 + 10 + c];
    }
}

// ---------------------------------------------------------------------------
extern "C" void kernel_launch(void* const* d_in, const int* in_sizes, int n_in,
                              void* d_out, int out_size, void* d_ws, size_t ws_size,
                              hipStream_t stream)
{
    (void)in_sizes; (void)n_in; (void)out_size; (void)ws_size;

    const float* features = (const float*)d_in[0];
    const float* w1 = (const float*)d_in[1];
    const float* b1 = (const float*)d_in[2];
    const float* w2 = (const float*)d_in[3];
    const float* b2 = (const float*)d_in[4];
    const float* w3 = (const float*)d_in[5];
    const float* b3 = (const float*)d_in[6];
    const float* w4 = (const float*)d_in[7];
    const float* b4 = (const float*)d_in[8];
    const float* fc1_w = (const float*)d_in[9];
    const float* fc1_b = (const float*)d_in[10];
    const float* fc2_w = (const float*)d_in[11];
    const float* fc2_b = (const float*)d_in[12];

    // ---- workspace plan (~191 MB) ----
    char* W = (char*)d_ws;
    size_t o = 0;
    auto alloc = [&](size_t bytes) -> char* {
        char* r = W + o; o += (bytes + 255) & ~(size_t)255; return r;
    };
    u16*   wT      = (u16*)  alloc(75497472ULL);  // 2*9*1024*2048*2 (per-layer reuse)
    u16*   xp      = (u16*)  alloc(33554432ULL);  // features: 2*16*256*2048*2
    u16*   actA    = (u16*)  alloc(16777216ULL);  // conv1 out: 2*16*256*1024*2
    float* a4      = (float*)alloc(3211264ULL);   // conv4 out fp32 NCHW
    float* partial = (float*)alloc(58720256ULL);  // max(4*1024*3200, 16*1024*896)*4
    float* fc1o    = (float*)alloc(262144ULL);
    float* part2   = (float*)alloc(3010560ULL);
    float* fc2o    = (float*)alloc(94080ULL);
    (void)alloc(4096);
    // aliases inside xp (dead after conv1's conv_mfma):
    float* part1 = (float*)xp;                    // 25.7MB, live fc1 only
    u16*   actB  = (u16*)(xp + (24u << 20) / 2);  // 5.3MB @ xp+24MB, conv2..conv4

    const long PSxp = 8388608L;   // 16*256*2048
    const long PSa  = 4194304L;   // 16*256*1024
    const long PSb  = 1327104L;   // 16*81*1024

    // features -> padded NHWC 2-plane (x16)
    pad_split<<<512, 256, 0, stream>>>(features, xp, 2048, 14, 14, 16, 256, PSxp);

    // conv1: Cin=2048; 27 phases * 32 cs = 864 steps, z=4 -> 216/block
    wsplit_kernel<<<dim3(8, 1024), 256, 0, stream>>>(w1, wT, 2048);
    hipMemsetAsync(actA, 0, 16777216ULL, stream);
    conv_mfma<1><<<dim3(4, 25, 4), 512, 0, stream>>>(
        xp, wT, partial, 2048, 16, 256, 14, 3136, 5, 216, 3200, PSxp);
    hipMemsetAsync(actB, 0, 5308416ULL, stream);       // xp dead; zero pads
    reduce_nhwc<<<dim3(16, 49), 256, 0, stream>>>(partial, b1, actA,
                                                  4, 3200, 3136, 14, 16, 256, PSa);

    // conv2: Cin=1024, stride 2; 27*16 = 432 steps, z=16 -> 27/block
    wsplit_kernel<<<dim3(4, 1024), 256, 0, stream>>>(w2, wT, 1024);
    conv_mfma<2><<<dim3(4, 7, 16), 512, 0, stream>>>(
        actA, wT, partial, 1024, 16, 256, 7, 784, 4, 27, 896, PSa);
    reduce_nhwc<<<dim3(16, 13), 256, 0, stream>>>(partial, b2, actB,
                                                  16, 896, 784, 7, 9, 81, PSb);

    // conv3: 7x7, padded 9x9
    wsplit_kernel<<<dim3(4, 1024), 256, 0, stream>>>(w3, wT, 1024);
    conv_mfma<1><<<dim3(4, 7, 16), 512, 0, stream>>>(
        actB, wT, partial, 1024, 9, 81, 7, 784, 4, 27, 896, PSb);
    reduce_nhwc<<<dim3(16, 13), 256, 0, stream>>>(partial, b3, actB,
                                                  16, 896, 784, 7, 9, 81, PSb);

    // conv4 -> fp32 NCHW a4
    wsplit_kernel<<<dim3(4, 1024), 256, 0, stream>>>(w4, wT, 1024);
    conv_mfma<1><<<dim3(4, 7, 16), 512, 0, stream>>>(
        actB, wT, partial, 1024, 9, 81, 7, 784, 4, 27, 896, PSb);
    reduce_f32<<<3136, 256, 0, stream>>>(partial, b4, a4, 16, 896, 784, 49);

    // fc1 (float4 loads, 98-way K-split) / fc2 / decode
    fc1_partial<<<dim3(4, 98), 256, 0, stream>>>(a4, fc1_w, part1);
    fc1_reduce<<<256, 256, 0, stream>>>(part1, fc1_b, fc1o);

    fc2_partial<<<dim3(6, 32), 256, 0, stream>>>(fc1o, fc2_w, part2);
    fc2_reduce<<<92, 256, 0, stream>>>(part2, fc2_b, fc2o);

    decode_nms<<<16, 128, 0, stream>>>(fc2o, (float*)d_out);
}